// Round 18
// baseline (86.496 us; speedup 1.0000x reference)
//
#include <hip/hip_runtime.h>
#include <stdint.h>
#include <stddef.h>

#define BATCH 65536
#define OUTF  1024
#define INF   128

typedef float f32x4 __attribute__((ext_vector_type(4)));
typedef __bf16 bf16x8 __attribute__((ext_vector_type(8)));

// RNE float->bf16, packed pair
__device__ inline uint32_t pack_bf16_rne(float a, float b) {
    uint32_t ua = __builtin_bit_cast(uint32_t, a);
    uint32_t ub = __builtin_bit_cast(uint32_t, b);
    ua += 0x7fffu + ((ua >> 16) & 1u);
    ub += 0x7fffu + ((ub >> 16) & 1u);
    return (ua >> 16) | (ub & 0xffff0000u);
}

// Prep: one wave per row. Writes bf16 rows in MFMA FRAGMENT ORDER
// (R14-verified swizzle) + row sum-of-squares.
// Tile t=row>>4, ks=k>>5, frag-lane wl=((k>>3)&3)*16+(row&15), elem j=k&7:
// bf16 addr = ((t*4+ks)*64 + wl)*8 + j -> GEMM fragment load is ONE
// contiguous 1KB instruction.
__global__ __launch_bounds__(256) void prep_kernel(
        const float* __restrict__ x, const float* __restrict__ w,
        float* __restrict__ sumsq, uint32_t* __restrict__ xb,
        uint32_t* __restrict__ wb) {
    int gtid = blockIdx.x * 256 + threadIdx.x;
    int row  = gtid >> 6;
    int lane = threadIdx.x & 63;
    if (row >= BATCH + OUTF) return;
    const float* src;
    uint32_t* dstbase;
    int r;
    if (row < BATCH) {
        src = x + (size_t)row * INF;
        dstbase = xb;
        r = row;
    } else {
        src = w + (size_t)(row - BATCH) * INF;
        dstbase = wb;
        r = row - BATCH;
    }
    float2 v = *(const float2*)(src + lane * 2);   // k = 2*lane, 2*lane+1
    int t    = r >> 4;
    int l16r = r & 15;
    int ks   = lane >> 4;
    int lq   = (lane >> 2) & 3;
    int sub  = lane & 3;
    dstbase[(((size_t)t * 4 + ks) * 64 + lq * 16 + l16r) * 4 + sub] =
        pack_bf16_rne(v.x, v.y);
    float s = v.x * v.x + v.y * v.y;
    #pragma unroll
    for (int off = 32; off; off >>= 1) s += __shfl_down(s, off);
    if (lane == 0) sumsq[row] = s;
}

#define TPAD 132  // LDS chunk row stride (floats)

// 128x128 tile per block, 4 waves (2x2). Frag-order loads (1KB insts) +
// chunked double-buffered epilogue (2 x [32][132] LDS = 34.8KB) ->
// 4 blocks/CU. Single-variable A/B vs R17: PLAIN stores instead of NT.
__global__ __launch_bounds__(256, 4) void gemm_epi_kernel(
        const __bf16* __restrict__ xb, const __bf16* __restrict__ wb,
        const float* __restrict__ x2, const float* __restrict__ w2,
        float* __restrict__ out) {
    // bijective XCD-chunked swizzle: nwg = 4096 (divisible by 8), nt fastest.
    int bid = blockIdx.x;
    int swz = (bid & 7) * (4096 / 8) + (bid >> 3);
    int mt = swz >> 3;          // 512 m-tiles
    int nt = swz & 7;           // 8 n-tiles
    int m0 = mt * 128, n0 = nt * 128;

    int tid  = threadIdx.x;
    int wid  = tid >> 6;
    int lane = tid & 63;
    int wr = wid >> 1, wc = wid & 1;    // 2x2 wave grid, 64x64 per wave
    int ta = (m0 + wr * 64) >> 4;       // A fragment-tile base
    int tb = (n0 + wc * 64) >> 4;       // B fragment-tile base

    __shared__ float sx2[128];
    __shared__ float sw2[128];
    __shared__ float tile2[2][32 * TPAD];
    if (tid < 128) {
        sx2[tid] = x2[m0 + tid];
        sw2[tid] = w2[n0 + tid];
    }
    __syncthreads();

    int l16 = lane & 15;   // fragment row/col (epilogue)
    int lq  = lane >> 4;   // row-quad selector (epilogue)

    f32x4 acc[4][4];
    #pragma unroll
    for (int i = 0; i < 4; ++i)
        #pragma unroll
        for (int j = 0; j < 4; ++j)
            acc[i][j] = f32x4{0.f, 0.f, 0.f, 0.f};

    #pragma unroll
    for (int ks = 0; ks < 4; ++ks) {
        bf16x8 a[4], b[4];
        #pragma unroll
        for (int im = 0; im < 4; ++im)
            a[im] = *(const bf16x8*)(
                xb + (((size_t)(ta + im) * 4 + ks) << 9) + lane * 8);
        #pragma unroll
        for (int in = 0; in < 4; ++in)
            b[in] = *(const bf16x8*)(
                wb + (((size_t)(tb + in) * 4 + ks) << 9) + lane * 8);
        #pragma unroll
        for (int im = 0; im < 4; ++im)
            #pragma unroll
            for (int in = 0; in < 4; ++in)
                acc[im][in] = __builtin_amdgcn_mfma_f32_16x16x32_bf16(
                    a[im], b[in], acc[im][in], 0, 0, 0);
    }

    // Chunked epilogue: chunk c = tile rows [32c, 32c+32), owned by waves
    // with wr == c>>1 (acc im in {(c&1)*2, (c&1)*2+1}); double-buffered.
    int srow = tid >> 3;          // 0..31  store row within chunk
    int scg  = tid & 7;           // 16B col group base
    #pragma unroll
    for (int c = 0; c < 4; ++c) {
        float* buf = tile2[c & 1];
        if (wr == (c >> 1)) {
            #pragma unroll
            for (int imh = 0; imh < 2; ++imh) {
                int im = (c & 1) * 2 + imh;
                #pragma unroll
                for (int in = 0; in < 4; ++in) {
                    #pragma unroll
                    for (int r = 0; r < 4; ++r) {
                        int row  = wr * 64 + im * 16 + lq * 4 + r;  // tile row
                        int rloc = row - c * 32;                     // 0..31
                        int col  = wc * 64 + in * 16 + l16;
                        float d2 = sx2[row] + sw2[col] - 2.0f * acc[im][in][r];
                        buf[rloc * TPAD + col] =
                            -0.5f * __builtin_amdgcn_sqrtf(fmaxf(d2, 0.0f));
                    }
                }
            }
        }
        __syncthreads();
        // all 256 threads store chunk c: 32 rows x 512B, PLAIN f32x4.
        size_t gbase = (size_t)(m0 + c * 32 + srow) * OUTF + n0;
        #pragma unroll
        for (int j = 0; j < 4; ++j) {
            int col4 = scg + j * 8;
            f32x4 v = *(const f32x4*)&buf[srow * TPAD + col4 * 4];
            *(f32x4*)&out[gbase + col4 * 4] = v;
        }
        // next chunk writes the other buffer; the barrier at the top of the
        // next iteration orders LDS reuse two chunks later.
    }
}

extern "C" void kernel_launch(void* const* d_in, const int* in_sizes, int n_in,
                              void* d_out, int out_size, void* d_ws, size_t ws_size,
                              hipStream_t stream) {
    const float* x = (const float*)d_in[0];
    const float* w = (const float*)d_in[1];
    float* out = (float*)d_out;

    // ws layout: [0, 66560*4) f32 sumsq (x2 then w2);
    // xb (frag-order bf16 x, 16 MiB) at byte 266240; wb after it.
    char* ws = (char*)d_ws;
    float* sumsq = (float*)ws;
    float* x2 = sumsq;
    float* w2 = sumsq + BATCH;
    uint32_t* xb_u32 = (uint32_t*)(ws + 266240);
    uint32_t* wb_u32 = (uint32_t*)(ws + 266240 + (size_t)BATCH * INF * 2);
    const __bf16* xb = (const __bf16*)xb_u32;
    const __bf16* wb = (const __bf16*)wb_u32;

    prep_kernel<<<dim3((BATCH + OUTF) / 4), dim3(256), 0, stream>>>(
        x, w, sumsq, xb_u32, wb_u32);
    gemm_epi_kernel<<<dim3(4096), dim3(256), 0, stream>>>(xb, wb, x2, w2, out);
}

// Round 19
// 73.407 us; speedup vs baseline: 1.1783x; 1.1783x over previous
//
#include <hip/hip_runtime.h>
#include <stdint.h>
#include <stddef.h>

#define BATCH 65536
#define OUTF  1024
#define INF   128

typedef float f32x4 __attribute__((ext_vector_type(4)));
typedef __bf16 bf16x8 __attribute__((ext_vector_type(8)));

#define CPAD 68   // wave scratch row stride (floats): 64 + 4

// RNE float->bf16, packed pair
__device__ inline uint32_t pack_bf16_rne(float a, float b) {
    uint32_t ua = __builtin_bit_cast(uint32_t, a);
    uint32_t ub = __builtin_bit_cast(uint32_t, b);
    ua += 0x7fffu + ((ua >> 16) & 1u);
    ub += 0x7fffu + ((ub >> 16) & 1u);
    return (ua >> 16) | (ub & 0xffff0000u);
}

// Load 8 contiguous fp32, accumulate sum of squares, return bf16x8 fragment.
__device__ inline bf16x8 load_frag_x2(const float* __restrict__ p, float& s) {
    f32x4 v0 = *(const f32x4*)(p);
    f32x4 v1 = *(const f32x4*)(p + 4);
    s += v0.x * v0.x + v0.y * v0.y + v0.z * v0.z + v0.w * v0.w
       + v1.x * v1.x + v1.y * v1.y + v1.z * v1.z + v1.w * v1.w;
    union { uint32_t u[4]; bf16x8 b; } f;
    f.u[0] = pack_bf16_rne(v0.x, v0.y);
    f.u[1] = pack_bf16_rne(v0.z, v0.w);
    f.u[2] = pack_bf16_rne(v1.x, v1.y);
    f.u[3] = pack_bf16_rne(v1.z, v1.w);
    return f.b;
}

// W prep: one wave per w-row. Writes wb in MFMA FRAGMENT ORDER (R14-verified)
// + row sumsq. Tile t=row>>4, ks=k>>5, frag-lane wl=((k>>3)&3)*16+(row&15),
// elem j=k&7: bf16 addr = ((t*4+ks)*64 + wl)*8 + j -> GEMM B-fragment load
// is ONE contiguous 1KB instruction.
__global__ __launch_bounds__(256) void wprep_kernel(
        const float* __restrict__ w, float* __restrict__ w2,
        uint32_t* __restrict__ wb) {
    int gtid = blockIdx.x * 256 + threadIdx.x;
    int row  = gtid >> 6;
    int lane = threadIdx.x & 63;
    if (row >= OUTF) return;
    const float* src = w + (size_t)row * INF;
    float2 v = *(const float2*)(src + lane * 2);   // k = 2*lane, 2*lane+1
    int t    = row >> 4;
    int l16r = row & 15;
    int ks   = lane >> 4;
    int lq   = (lane >> 2) & 3;
    int sub  = lane & 3;
    wb[(((size_t)t * 4 + ks) * 64 + lq * 16 + l16r) * 4 + sub] =
        pack_bf16_rne(v.x, v.y);
    float s = v.x * v.x + v.y * v.y;
    #pragma unroll
    for (int off = 32; off; off >>= 1) s += __shfl_down(s, off);
    if (lane == 0) w2[row] = s;
}

// Fused kernel: block = 16 x-rows x ALL 1024 cols (grid 4096, 4/CU).
// x converted in-block ONCE (each x-row touched by exactly one block -> no
// xprep pass, no xb HBM bounce). Wave owns a 256-col slice, processed as
// 4 sub-chunks of 64 cols: B-frags are contiguous 1KB loads from frag-order
// wb (L2-resident), 16 MFMA, epilogue -> wave-private dbuf LDS scratch,
// NT f32x4 stores (1KB/inst) issued per sub-chunk -> stores spread across
// the block's whole life. ONE barrier total (sw2 staging).
__global__ __launch_bounds__(256, 4) void fused_kernel(
        const float* __restrict__ x, const __bf16* __restrict__ wb,
        const float* __restrict__ w2, float* __restrict__ out) {
    int tid  = threadIdx.x;
    int wid  = tid >> 6;        // wave -> col slice [wid*256, wid*256+256)
    int lane = tid & 63;
    int l16  = lane & 15;       // fragment row/col
    int lq   = lane >> 4;       // k-quarter (loads) / row-quad (epilogue)

    int rbase = blockIdx.x * 16;   // block's 16 x-rows

    __shared__ float sw2[OUTF];
    __shared__ float scratch[4][2][16 * CPAD];   // [wave][dbuf][row][col]
    #pragma unroll
    for (int j = 0; j < 4; ++j)
        sw2[tid + 256 * j] = w2[tid + 256 * j];

    // A fragments: 16 rows, k = ks*32 + lq*8 (16 VGPR) + x2 partial.
    bf16x8 a[4];
    float x2p = 0.f;
    #pragma unroll
    for (int ks = 0; ks < 4; ++ks)
        a[ks] = load_frag_x2(
            &x[(size_t)(rbase + l16) * INF + ks * 32 + lq * 8], x2p);

    // Row sumsq butterfly over k-quarter groups; redistribute to epilogue rows.
    x2p += __shfl_xor(x2p, 16);
    x2p += __shfl_xor(x2p, 32);
    float x2row[4];
    #pragma unroll
    for (int r = 0; r < 4; ++r)
        x2row[r] = __shfl(x2p, lq * 20 + r);

    __syncthreads();   // sw2 ready — the ONLY barrier

    #pragma unroll
    for (int sc = 0; sc < 4; ++sc) {
        int c0  = wid * 256 + sc * 64;          // sub-chunk column base
        int tb0 = (c0 >> 4);                    // fragment-tile base
        float* buf = scratch[wid][sc & 1];

        f32x4 acc[4];
        #pragma unroll
        for (int in = 0; in < 4; ++in)
            acc[in] = f32x4{0.f, 0.f, 0.f, 0.f};

        #pragma unroll
        for (int ks = 0; ks < 4; ++ks) {
            bf16x8 b[4];
            #pragma unroll
            for (int in = 0; in < 4; ++in)
                b[in] = *(const bf16x8*)(
                    wb + (((size_t)(tb0 + in) * 4 + ks) << 9) + lane * 8);
            #pragma unroll
            for (int in = 0; in < 4; ++in)
                acc[in] = __builtin_amdgcn_mfma_f32_16x16x32_bf16(
                    a[ks], b[in], acc[in], 0, 0, 0);
        }

        // Epilogue into wave-private scratch (C/D: col=l16, row=lq*4+r).
        #pragma unroll
        for (int in = 0; in < 4; ++in) {
            #pragma unroll
            for (int r = 0; r < 4; ++r) {
                int row = lq * 4 + r;                 // 0..15
                int col = in * 16 + l16;              // 0..63
                float d2 = x2row[r] + sw2[c0 + col] - 2.0f * acc[in][r];
                buf[row * CPAD + col] =
                    -0.5f * __builtin_amdgcn_sqrtf(fmaxf(d2, 0.0f));
            }
        }
        // Intra-wave ds_write->ds_read ordering via lgkmcnt; no barrier.

        // Store sub-chunk: 16 rows x 256B segments; each inst = 4 rows x
        // 256B = 1KB (lane lq -> row group, l16 -> 16B col group). NT.
        #pragma unroll
        for (int k = 0; k < 4; ++k) {
            int row = k * 4 + lq;
            f32x4 v = *(const f32x4*)&buf[row * CPAD + l16 * 4];
            __builtin_nontemporal_store(
                v, (f32x4*)&out[(size_t)(rbase + row) * OUTF + c0 + l16 * 4]);
        }
    }
}

extern "C" void kernel_launch(void* const* d_in, const int* in_sizes, int n_in,
                              void* d_out, int out_size, void* d_ws, size_t ws_size,
                              hipStream_t stream) {
    const float* x = (const float*)d_in[0];
    const float* w = (const float*)d_in[1];
    float* out = (float*)d_out;

    // ws layout: w2 [1024 f32] at 0; wb (frag-order bf16 W, 256KB) at 4096.
    char* ws = (char*)d_ws;
    float* w2 = (float*)ws;
    uint32_t* wb_u32 = (uint32_t*)(ws + 4096);
    const __bf16* wb = (const __bf16*)wb_u32;

    wprep_kernel<<<dim3(OUTF / 4), dim3(256), 0, stream>>>(w, w2, wb_u32);
    fused_kernel<<<dim3(BATCH / 16), dim3(256), 0, stream>>>(x, wb, w2, out);
}

// Round 20
// 73.015 us; speedup vs baseline: 1.1846x; 1.0054x over previous
//
#include <hip/hip_runtime.h>
#include <stdint.h>
#include <stddef.h>

#define BATCH 65536
#define OUTF  1024
#define INF   128

typedef float f32x4 __attribute__((ext_vector_type(4)));
typedef __bf16 bf16x8 __attribute__((ext_vector_type(8)));

#define CPAD 132   // wave scratch row stride (floats): 128 + 4

// RNE float->bf16, packed pair
__device__ inline uint32_t pack_bf16_rne(float a, float b) {
    uint32_t ua = __builtin_bit_cast(uint32_t, a);
    uint32_t ub = __builtin_bit_cast(uint32_t, b);
    ua += 0x7fffu + ((ua >> 16) & 1u);
    ub += 0x7fffu + ((ub >> 16) & 1u);
    return (ua >> 16) | (ub & 0xffff0000u);
}

// Load 8 contiguous fp32, accumulate sum of squares, return bf16x8 fragment.
__device__ inline bf16x8 load_frag_x2(const float* __restrict__ p, float& s) {
    f32x4 v0 = *(const f32x4*)(p);
    f32x4 v1 = *(const f32x4*)(p + 4);
    s += v0.x * v0.x + v0.y * v0.y + v0.z * v0.z + v0.w * v0.w
       + v1.x * v1.x + v1.y * v1.y + v1.z * v1.z + v1.w * v1.w;
    union { uint32_t u[4]; bf16x8 b; } f;
    f.u[0] = pack_bf16_rne(v0.x, v0.y);
    f.u[1] = pack_bf16_rne(v0.z, v0.w);
    f.u[2] = pack_bf16_rne(v1.x, v1.y);
    f.u[3] = pack_bf16_rne(v1.z, v1.w);
    return f.b;
}

// W prep: one wave per w-row. Writes wb in MFMA FRAGMENT ORDER (R14-verified)
// + row sumsq. Tile t=row>>4, ks=k>>5, frag-lane wl=((k>>3)&3)*16+(row&15),
// elem j=k&7: bf16 addr = ((t*4+ks)*64 + wl)*8 + j -> GEMM B-fragment load
// is ONE contiguous 1KB instruction.
__global__ __launch_bounds__(256) void wprep_kernel(
        const float* __restrict__ w, float* __restrict__ w2,
        uint32_t* __restrict__ wb) {
    int gtid = blockIdx.x * 256 + threadIdx.x;
    int row  = gtid >> 6;
    int lane = threadIdx.x & 63;
    if (row >= OUTF) return;
    const float* src = w + (size_t)row * INF;
    float2 v = *(const float2*)(src + lane * 2);   // k = 2*lane, 2*lane+1
    int t    = row >> 4;
    int l16r = row & 15;
    int ks   = lane >> 4;
    int lq   = (lane >> 2) & 3;
    int sub  = lane & 3;
    wb[(((size_t)t * 4 + ks) * 64 + lq * 16 + l16r) * 4 + sub] =
        pack_bf16_rne(v.x, v.y);
    float s = v.x * v.x + v.y * v.y;
    #pragma unroll
    for (int off = 32; off; off >>= 1) s += __shfl_down(s, off);
    if (lane == 0) w2[row] = s;
}

// Fused kernel (R19 + paired-sub-chunk stores): block = 16 x-rows x all 1024
// cols (grid 4096, 4/CU). Wave owns a 256-col slice as 4 sub-chunks of 64;
// pairs of sub-chunks accumulate into a single per-wave [16][132] LDS buffer,
// then stored as 512B-per-row segments (each NT inst = 2 rows x 512B = 1KB).
// Single-buffered scratch is WAR-safe: same-wave LDS ops execute in order
// (the pair's store ds_reads precede the next pair's epilogue ds_writes).
// ONE barrier total (sw2 staging).
__global__ __launch_bounds__(256, 4) void fused_kernel(
        const float* __restrict__ x, const __bf16* __restrict__ wb,
        const float* __restrict__ w2, float* __restrict__ out) {
    int tid  = threadIdx.x;
    int wid  = tid >> 6;        // wave -> col slice [wid*256, wid*256+256)
    int lane = tid & 63;
    int l16  = lane & 15;       // fragment row/col
    int lq   = lane >> 4;       // k-quarter (loads) / row-quad (epilogue)

    int rbase = blockIdx.x * 16;   // block's 16 x-rows

    __shared__ float sw2[OUTF];
    __shared__ float scratch[4][16 * CPAD];   // per-wave [16][132]
    #pragma unroll
    for (int j = 0; j < 4; ++j)
        sw2[tid + 256 * j] = w2[tid + 256 * j];

    // A fragments: 16 rows, k = ks*32 + lq*8 (16 VGPR) + x2 partial.
    bf16x8 a[4];
    float x2p = 0.f;
    #pragma unroll
    for (int ks = 0; ks < 4; ++ks)
        a[ks] = load_frag_x2(
            &x[(size_t)(rbase + l16) * INF + ks * 32 + lq * 8], x2p);

    // Row sumsq butterfly over k-quarter groups; redistribute to epilogue rows.
    x2p += __shfl_xor(x2p, 16);
    x2p += __shfl_xor(x2p, 32);
    float x2row[4];
    #pragma unroll
    for (int r = 0; r < 4; ++r)
        x2row[r] = __shfl(x2p, lq * 20 + r);

    __syncthreads();   // sw2 ready — the ONLY barrier

    float* buf = scratch[wid];

    #pragma unroll
    for (int sc = 0; sc < 4; ++sc) {
        int c0  = wid * 256 + sc * 64;          // sub-chunk column base
        int tb0 = c0 >> 4;                      // fragment-tile base
        int cb  = (sc & 1) * 64;                // column offset within buf

        f32x4 acc[4];
        #pragma unroll
        for (int in = 0; in < 4; ++in)
            acc[in] = f32x4{0.f, 0.f, 0.f, 0.f};

        #pragma unroll
        for (int ks = 0; ks < 4; ++ks) {
            bf16x8 b[4];
            #pragma unroll
            for (int in = 0; in < 4; ++in)
                b[in] = *(const bf16x8*)(
                    wb + (((size_t)(tb0 + in) * 4 + ks) << 9) + lane * 8);
            #pragma unroll
            for (int in = 0; in < 4; ++in)
                acc[in] = __builtin_amdgcn_mfma_f32_16x16x32_bf16(
                    a[ks], b[in], acc[in], 0, 0, 0);
        }

        // Epilogue into wave-private scratch (C/D: col=l16, row=lq*4+r).
        #pragma unroll
        for (int in = 0; in < 4; ++in) {
            #pragma unroll
            for (int r = 0; r < 4; ++r) {
                int row = lq * 4 + r;                 // 0..15
                int col = cb + in * 16 + l16;         // 0..127
                float d2 = x2row[r] + sw2[c0 + col - cb] - 2.0f * acc[in][r];
                buf[row * CPAD + col] =
                    -0.5f * __builtin_amdgcn_sqrtf(fmaxf(d2, 0.0f));
            }
        }
        // Intra-wave ds_write->ds_read ordering via lgkmcnt; no barrier.

        // After each PAIR of sub-chunks: store 16 rows x 512B segments.
        // Each NT inst = 1KB = 2 rows x 512B (lane>>5 -> row parity,
        // lane&31 -> 16B col group).
        if (sc & 1) {
            int cp0 = wid * 256 + (sc >> 1) * 128;
            #pragma unroll
            for (int k = 0; k < 8; ++k) {
                int row = k * 2 + (lane >> 5);
                f32x4 v = *(const f32x4*)&buf[row * CPAD + (lane & 31) * 4];
                __builtin_nontemporal_store(
                    v, (f32x4*)&out[(size_t)(rbase + row) * OUTF + cp0 + (lane & 31) * 4]);
            }
        }
    }
}

extern "C" void kernel_launch(void* const* d_in, const int* in_sizes, int n_in,
                              void* d_out, int out_size, void* d_ws, size_t ws_size,
                              hipStream_t stream) {
    const float* x = (const float*)d_in[0];
    const float* w = (const float*)d_in[1];
    float* out = (float*)d_out;

    // ws layout: w2 [1024 f32] at 0; wb (frag-order bf16 W, 256KB) at 4096.
    char* ws = (char*)d_ws;
    float* w2 = (float*)ws;
    uint32_t* wb_u32 = (uint32_t*)(ws + 4096);
    const __bf16* wb = (const __bf16*)wb_u32;

    wprep_kernel<<<dim3(OUTF / 4), dim3(256), 0, stream>>>(w, w2, wb_u32);
    fused_kernel<<<dim3(BATCH / 16), dim3(256), 0, stream>>>(x, wb, w2, out);
}